// Round 11
// baseline (724.900 us; speedup 1.0000x reference)
//
#include <hip/hip_runtime.h>

#define S_LEN 2048
#define NH 16
#define DH 64
#define DM 1024
#define NB 2
#define BS 4096  // NB*S_LEN

typedef __attribute__((ext_vector_type(4))) float f32x4;
typedef __attribute__((ext_vector_type(8))) short bfrag;  // 8 bf16 in 4 VGPRs

__device__ __forceinline__ unsigned short f2bf(float f) {
    unsigned u = __builtin_bit_cast(unsigned, f);
    u += 0x7FFFu + ((u >> 16) & 1u);
    return (unsigned short)(u >> 16);
}

// async global->LDS, 16B per lane; LDS dest must be wave-uniform base (+lane*16 implicit)
__device__ __forceinline__ void gld16(const unsigned short* g, unsigned short* l) {
    __builtin_amdgcn_global_load_lds((const __attribute__((address_space(1))) void*)g,
                                     (__attribute__((address_space(3))) void*)l, 16, 0, 0);
}

// ---------------- all 7 fp32 -> bf16 casts in one kernel ----------------
__global__ __launch_bounds__(256) void cast_all(const float* __restrict__ Q,
                                                const float* __restrict__ K,
                                                const float* __restrict__ V,
                                                const float* __restrict__ Wq,
                                                const float* __restrict__ Wk,
                                                const float* __restrict__ Wv,
                                                const float* __restrict__ Wo,
                                                unsigned short* __restrict__ Qc,
                                                unsigned short* __restrict__ Kc,
                                                unsigned short* __restrict__ Vc,
                                                unsigned short* __restrict__ Wqc,
                                                unsigned short* __restrict__ Wkc,
                                                unsigned short* __restrict__ Wvc,
                                                unsigned short* __restrict__ Woc) {
    int i = blockIdx.x * 256 + threadIdx.x;  // over 4,194,304 float4 chunks
    const float* src;
    unsigned short* dst;
    int off;
    if (i < 3145728) {                       // Q/K/V: 3 x 2^20 chunks
        int w = i >> 20;
        off = i & 1048575;
        src = (w == 0) ? Q : (w == 1) ? K : V;
        dst = (w == 0) ? Qc : (w == 1) ? Kc : Vc;
    } else {                                 // weights: 4 x 2^18 chunks
        int j = i - 3145728;
        int w = j >> 18;
        off = j & 262143;
        src = (w == 0) ? Wq : (w == 1) ? Wk : (w == 2) ? Wv : Wo;
        dst = (w == 0) ? Wqc : (w == 1) ? Wkc : (w == 2) ? Wvc : Woc;
    }
    float4 v = reinterpret_cast<const float4*>(src)[off];
    ushort4 o;
    o.x = f2bf(v.x); o.y = f2bf(v.y); o.z = f2bf(v.z); o.w = f2bf(v.w);
    reinterpret_cast<ushort4*>(dst)[off] = o;
}

// ================= combined QKV projection (m97 structure) =================
__global__ __launch_bounds__(256) void gemm_qkv(const unsigned short* __restrict__ Qc,
                                                const unsigned short* __restrict__ Kc,
                                                const unsigned short* __restrict__ Vc,
                                                const unsigned short* __restrict__ Wqc,
                                                const unsigned short* __restrict__ Wkc,
                                                const unsigned short* __restrict__ Wvc,
                                                unsigned short* __restrict__ qh,
                                                unsigned short* __restrict__ kh,
                                                unsigned short* __restrict__ vT) {
    const int z = blockIdx.z;
    const unsigned short* A = (z == 0) ? Qc : (z == 1) ? Kc : Vc;
    const unsigned short* B = (z == 0) ? Wqc : (z == 1) ? Wkc : Wvc;
    const int tid = threadIdx.x, lane = tid & 63;
    const int l15 = lane & 15, lhi = lane >> 4;
    const int w = tid >> 6, wr = w >> 1, wc = w & 1;
    const int m0 = blockIdx.y * 128, n0 = blockIdx.x * 128;
    const int K = DM;
    const int lr8 = lane >> 3;             // row-in-8-row-group
    const int csw = (lane & 7) ^ lr8;      // swizzled 16B-chunk index (8 chunks/row)

    __shared__ unsigned short sA[128 * 64];
    __shared__ unsigned short sB[128 * 64];

    f32x4 acc[4][4];
#pragma unroll
    for (int i = 0; i < 4; ++i)
#pragma unroll
        for (int j = 0; j < 4; ++j) acc[i][j] = (f32x4){0.f, 0.f, 0.f, 0.f};

    for (int t = 0; t < 16; ++t) {
        const int k0 = t * 64;
#pragma unroll
        for (int i = 0; i < 4; ++i) {
            int g = w * 4 + i;
            int row = g * 8 + lr8;
            gld16(A + (size_t)(m0 + row) * K + k0 + csw * 8, sA + g * 512);
            gld16(B + (size_t)(n0 + row) * K + k0 + csw * 8, sB + g * 512);
        }
        __syncthreads();
#pragma unroll
        for (int kk = 0; kk < 2; ++kk) {
            bfrag a[4], b[4];
#pragma unroll
            for (int f = 0; f < 4; ++f) {
                int ra = wr * 64 + f * 16 + l15;
                a[f] = *reinterpret_cast<const bfrag*>(
                    sA + ra * 64 + (((kk * 4 + lhi) ^ (ra & 7)) << 3));
                int rb = wc * 64 + f * 16 + l15;
                b[f] = *reinterpret_cast<const bfrag*>(
                    sB + rb * 64 + (((kk * 4 + lhi) ^ (rb & 7)) << 3));
            }
#pragma unroll
            for (int fm = 0; fm < 4; ++fm)
#pragma unroll
                for (int fn = 0; fn < 4; ++fn)
                    acc[fm][fn] =
                        __builtin_amdgcn_mfma_f32_16x16x32_bf16(a[fm], b[fn], acc[fm][fn], 0, 0, 0);
        }
        __syncthreads();
    }

    if (z == 2) {
#pragma unroll
        for (int fm = 0; fm < 4; ++fm)
#pragma unroll
            for (int fn = 0; fn < 4; ++fn) {
                int sbase = m0 + wr * 64 + fm * 16 + (lhi << 2);
                int gcol = n0 + wc * 64 + fn * 16 + l15;
                int b = sbase >> 11, s = sbase & 2047, h = gcol >> 6, d = gcol & 63;
                ushort4 o;
                o.x = f2bf(acc[fm][fn][0]); o.y = f2bf(acc[fm][fn][1]);
                o.z = f2bf(acc[fm][fn][2]); o.w = f2bf(acc[fm][fn][3]);
                *reinterpret_cast<ushort4*>(vT + ((size_t)(b * NH + h) * DH + d) * S_LEN + s) = o;
            }
    } else {
        unsigned short* Out = (z == 0) ? qh : kh;
#pragma unroll
        for (int fm = 0; fm < 4; ++fm)
#pragma unroll
            for (int fn = 0; fn < 4; ++fn)
#pragma unroll
                for (int r = 0; r < 4; ++r) {
                    int grow = m0 + wr * 64 + fm * 16 + (lhi << 2) + r;
                    int gcol = n0 + wc * 64 + fn * 16 + l15;
                    int b = grow >> 11, s = grow & 2047, h = gcol >> 6, d = gcol & 63;
                    Out[((size_t)(b * NH + h) * S_LEN + s) * DH + d] = f2bf(acc[fm][fn][r]);
                }
    }
}

// ================= output projection =================
__global__ __launch_bounds__(256) void gemm_out(const unsigned short* __restrict__ A,
                                                const unsigned short* __restrict__ B,
                                                float* __restrict__ Out) {
    const int tid = threadIdx.x, lane = tid & 63;
    const int l15 = lane & 15, lhi = lane >> 4;
    const int w = tid >> 6, wr = w >> 1, wc = w & 1;
    const int m0 = blockIdx.y * 128, n0 = blockIdx.x * 128;
    const int K = DM, N = DM;
    const int lr8 = lane >> 3;
    const int csw = (lane & 7) ^ lr8;

    __shared__ unsigned short sA[128 * 64];
    __shared__ unsigned short sB[128 * 64];

    f32x4 acc[4][4];
#pragma unroll
    for (int i = 0; i < 4; ++i)
#pragma unroll
        for (int j = 0; j < 4; ++j) acc[i][j] = (f32x4){0.f, 0.f, 0.f, 0.f};

    for (int t = 0; t < 16; ++t) {
        const int k0 = t * 64;
#pragma unroll
        for (int i = 0; i < 4; ++i) {
            int g = w * 4 + i;
            int row = g * 8 + lr8;
            gld16(A + (size_t)(m0 + row) * K + k0 + csw * 8, sA + g * 512);
            gld16(B + (size_t)(n0 + row) * K + k0 + csw * 8, sB + g * 512);
        }
        __syncthreads();
#pragma unroll
        for (int kk = 0; kk < 2; ++kk) {
            bfrag a[4], b[4];
#pragma unroll
            for (int f = 0; f < 4; ++f) {
                int ra = wr * 64 + f * 16 + l15;
                a[f] = *reinterpret_cast<const bfrag*>(
                    sA + ra * 64 + (((kk * 4 + lhi) ^ (ra & 7)) << 3));
                int rb = wc * 64 + f * 16 + l15;
                b[f] = *reinterpret_cast<const bfrag*>(
                    sB + rb * 64 + (((kk * 4 + lhi) ^ (rb & 7)) << 3));
            }
#pragma unroll
            for (int fm = 0; fm < 4; ++fm)
#pragma unroll
                for (int fn = 0; fn < 4; ++fn)
                    acc[fm][fn] =
                        __builtin_amdgcn_mfma_f32_16x16x32_bf16(a[fm], b[fn], acc[fm][fn], 0, 0, 0);
        }
        __syncthreads();
    }

#pragma unroll
    for (int fm = 0; fm < 4; ++fm)
#pragma unroll
        for (int fn = 0; fn < 4; ++fn)
#pragma unroll
            for (int r = 0; r < 4; ++r) {
                int grow = m0 + wr * 64 + fm * 16 + (lhi << 2) + r;
                int gcol = n0 + wc * 64 + fn * 16 + l15;
                Out[(size_t)grow * N + gcol] = acc[fm][fn][r];
            }
}

// ================= fused scores + softmax + PV: 1-WAVE blocks =================
// Block = ONE wave (64 threads), 16 q-rows; grid 4096 blocks -> 16 independent
// waves/CU, whole grid resident, zero barriers, zero LDS, no convoying.
// Load-after-use prefetch: kf/vf/sv reloaded immediately after their consumer,
// so the following VALU chain (softmax / exp+pack) covers L2 latency.
__global__ __launch_bounds__(64, 4) void attn_fused(const unsigned short* __restrict__ qh,
                                                    const unsigned short* __restrict__ kh,
                                                    const unsigned short* __restrict__ vT,
                                                    const float* __restrict__ prev,
                                                    float* __restrict__ scores,
                                                    float* __restrict__ attn,
                                                    unsigned short* __restrict__ ctx) {
    const int z = blockIdx.z;         // b*NH + h
    const int m0 = blockIdx.x * 16;   // Q strip base (16 rows per 1-wave block)
    const int lane = threadIdx.x & 63;
    const int l15 = lane & 15, lhi = lane >> 4;

    const unsigned short* Qz = qh + (size_t)z * S_LEN * DH;
    const unsigned short* Kz = kh + (size_t)z * S_LEN * DH;
    const unsigned short* Vz = vT + (size_t)z * DH * S_LEN;
    const size_t zbase = (size_t)z * S_LEN * S_LEN;
    const float scale = 0.125f;  // 1/sqrt(64)

    const int qrow = l15;             // local q row this lane owns
    const float* prevRow = prev + zbase + (size_t)(m0 + qrow) * S_LEN;
    float* scoresRow = scores + zbase + (size_t)(m0 + qrow) * S_LEN;
    float* attnRow = attn + zbase + (size_t)(m0 + qrow) * S_LEN;
    const int c4 = lhi * 4;           // phase-1 col offset within 16-group
    const int c8 = lhi * 8;           // phase-2 pf-order col offset within 32-group

    // Q fragments: loaded once (8 VGPRs)
    bfrag qf[2];
#pragma unroll
    for (int kk = 0; kk < 2; ++kk)
        qf[kk] = *reinterpret_cast<const bfrag*>(Qz + (size_t)(m0 + qrow) * DH + kk * 32 +
                                                 lhi * 8);

    float m_r = -1e30f, l_r = 0.f;

    // prologue: K tile 0 + prev tile 0
    bfrag kf[2][4];
#pragma unroll
    for (int kk = 0; kk < 2; ++kk)
#pragma unroll
        for (int f = 0; f < 4; ++f)
            kf[kk][f] = *reinterpret_cast<const bfrag*>(
                Kz + (size_t)(f * 16 + l15) * DH + kk * 32 + lhi * 8);
    f32x4 pv4[4];
#pragma unroll
    for (int f = 0; f < 4; ++f)
        pv4[f] = __builtin_nontemporal_load(
            reinterpret_cast<const f32x4*>(prevRow + f * 16 + c4));

    // ---------- phase 1: 32 x 64-col tiles ----------
    for (int kt = 0; kt < 32; ++kt) {
        const int n0 = kt * 64;

        f32x4 acc[4];
#pragma unroll
        for (int f = 0; f < 4; ++f) acc[f] = (f32x4){0.f, 0.f, 0.f, 0.f};
#pragma unroll
        for (int kk = 0; kk < 2; ++kk)
#pragma unroll
            for (int f = 0; f < 4; ++f)
                acc[f] = __builtin_amdgcn_mfma_f32_16x16x32_bf16(kf[kk][f], qf[kk], acc[f], 0, 0, 0);

        // reload kf for kt+1 NOW (WAR ok; waited at next iter's first MFMA,
        // covered by the softmax chain below)
        if (kt < 31) {
            const int n1 = n0 + 64;
#pragma unroll
            for (int kk = 0; kk < 2; ++kk)
#pragma unroll
                for (int f = 0; f < 4; ++f)
                    kf[kk][f] = *reinterpret_cast<const bfrag*>(
                        Kz + (size_t)(n1 + f * 16 + l15) * DH + kk * 32 + lhi * 8);
        }

        // consume prev(kt); immediately refill prev(kt+1)
#pragma unroll
        for (int f = 0; f < 4; ++f)
#pragma unroll
            for (int r = 0; r < 4; ++r) acc[f][r] = acc[f][r] * scale + pv4[f][r];
        if (kt < 31) {
            const int n1 = n0 + 64;
#pragma unroll
            for (int f = 0; f < 4; ++f)
                pv4[f] = __builtin_nontemporal_load(
                    reinterpret_cast<const f32x4*>(prevRow + n1 + f * 16 + c4));
        }
#pragma unroll
        for (int f = 0; f < 4; ++f)
            *reinterpret_cast<f32x4*>(scoresRow + n0 + f * 16 + c4) = acc[f];

        // online softmax (row q spread over lanes l15, l15^16, l15^32, l15^48)
        float pm = acc[0][0];
#pragma unroll
        for (int f = 0; f < 4; ++f)
#pragma unroll
            for (int r = 0; r < 4; ++r) pm = fmaxf(pm, acc[f][r]);
        pm = fmaxf(pm, __shfl_xor(pm, 16));
        pm = fmaxf(pm, __shfl_xor(pm, 32));
        float mnew = fmaxf(m_r, pm);
        float psum = 0.f;
#pragma unroll
        for (int f = 0; f < 4; ++f)
#pragma unroll
            for (int r = 0; r < 4; ++r) psum += __expf(acc[f][r] - mnew);
        psum += __shfl_xor(psum, 16);
        psum += __shfl_xor(psum, 32);
        l_r = l_r * __expf(m_r - mnew) + psum;
        m_r = mnew;
    }

    const float inv_l = 1.0f / l_r;

    // ---------- phase 2: reverse order (hottest scores first) ----------
    f32x4 acco[4];
#pragma unroll
    for (int f = 0; f < 4; ++f) acco[f] = (f32x4){0.f, 0.f, 0.f, 0.f};

    // prologue: V tile 31 + scores tile 31 (pf-order cols kk*32 + c8 + h*4)
    bfrag vf[2][4];
#pragma unroll
    for (int kk = 0; kk < 2; ++kk)
#pragma unroll
        for (int f = 0; f < 4; ++f)
            vf[kk][f] = *reinterpret_cast<const bfrag*>(
                Vz + (size_t)(f * 16 + l15) * S_LEN + 31 * 64 + kk * 32 + lhi * 8);
    f32x4 sv[2][2];
#pragma unroll
    for (int kk = 0; kk < 2; ++kk)
#pragma unroll
        for (int h = 0; h < 2; ++h)
            sv[kk][h] = *reinterpret_cast<const f32x4*>(scoresRow + 31 * 64 + kk * 32 + c8 + h * 4);

    for (int kt = 31; kt >= 0; --kt) {
        const int n0 = kt * 64;
        // p = exp(s-m)/l; write attn (NT); pack pf lane-locally (pf-order)
        bfrag pf[2];
#pragma unroll
        for (int kk = 0; kk < 2; ++kk) {
#pragma unroll
            for (int h = 0; h < 2; ++h) {
                f32x4 p4;
#pragma unroll
                for (int r = 0; r < 4; ++r) p4[r] = __expf(sv[kk][h][r] - m_r) * inv_l;
                __builtin_nontemporal_store(
                    p4, reinterpret_cast<f32x4*>(attnRow + n0 + kk * 32 + c8 + h * 4));
#pragma unroll
                for (int r = 0; r < 4; ++r) pf[kk][h * 4 + r] = (short)f2bf(p4[r]);
            }
        }
        // refill sv(kt-1) now (waited at next iter's exp chain; covered by MFMAs)
        if (kt > 0) {
            const int n1 = n0 - 64;
#pragma unroll
            for (int kk = 0; kk < 2; ++kk)
#pragma unroll
                for (int h = 0; h < 2; ++h)
                    sv[kk][h] =
                        *reinterpret_cast<const f32x4*>(scoresRow + n1 + kk * 32 + c8 + h * 4);
        }
#pragma unroll
        for (int kk = 0; kk < 2; ++kk)
#pragma unroll
            for (int f = 0; f < 4; ++f)
                acco[f] = __builtin_amdgcn_mfma_f32_16x16x32_bf16(vf[kk][f], pf[kk], acco[f], 0, 0, 0);
        // reload vf for kt-1 right after consumption (covered by next exp chain)
        if (kt > 0) {
            const int n1 = n0 - 64;
#pragma unroll
            for (int kk = 0; kk < 2; ++kk)
#pragma unroll
                for (int f = 0; f < 4; ++f)
                    vf[kk][f] = *reinterpret_cast<const bfrag*>(
                        Vz + (size_t)(f * 16 + l15) * S_LEN + n1 + kk * 32 + lhi * 8);
        }
    }

    // write ctx (b, s, h*DH + d) bf16; lane owns q-row, d = f*16 + lhi*4 + r
    const int b = z >> 4, h = z & 15;
    const int s = m0 + qrow;
#pragma unroll
    for (int f = 0; f < 4; ++f) {
        int d0 = f * 16 + c4;
        ushort4 o;
        o.x = f2bf(acco[f][0]); o.y = f2bf(acco[f][1]);
        o.z = f2bf(acco[f][2]); o.w = f2bf(acco[f][3]);
        *reinterpret_cast<ushort4*>(ctx + ((size_t)(b * S_LEN + s)) * DM + h * DH + d0) = o;
    }
}

extern "C" void kernel_launch(void* const* d_in, const int* in_sizes, int n_in, void* d_out,
                              int out_size, void* d_ws, size_t ws_size, hipStream_t stream) {
    const float* Q = (const float*)d_in[0];
    const float* K = (const float*)d_in[1];
    const float* V = (const float*)d_in[2];
    const float* prev = (const float*)d_in[3];
    const float* Wq = (const float*)d_in[4];
    const float* Wk = (const float*)d_in[5];
    const float* Wv = (const float*)d_in[6];
    const float* Wo = (const float*)d_in[7];

    float* out = (float*)d_out;
    float* attn = out + (size_t)BS * DM;
    float* scores = attn + (size_t)NB * NH * S_LEN * S_LEN;

    unsigned short* ws = (unsigned short*)d_ws;
    unsigned short* Qc = ws;
    unsigned short* Kc = Qc + (size_t)BS * DM;
    unsigned short* Vc = Kc + (size_t)BS * DM;
    unsigned short* Wqc = Vc + (size_t)BS * DM;
    unsigned short* Wkc = Wqc + (size_t)DM * DM;
    unsigned short* Wvc = Wkc + (size_t)DM * DM;
    unsigned short* Woc = Wvc + (size_t)DM * DM;
    unsigned short* qh = Woc + (size_t)DM * DM;    // (b,h,s,d) bf16
    unsigned short* kh = qh + (size_t)BS * DM;     // (b,h,s,d) bf16
    unsigned short* vT = kh + (size_t)BS * DM;     // (b,h,d,s) bf16
    unsigned short* ctx = vT + (size_t)BS * DM;    // (b,s,h*d) bf16

    // all casts in one launch
    cast_all<<<16384, 256, 0, stream>>>(Q, K, V, Wq, Wk, Wv, Wo,
                                        Qc, Kc, Vc, Wqc, Wkc, Wvc, Woc);

    // combined QKV projections (768 blocks)
    dim3 gq(DM / 128, BS / 128, 3);
    gemm_qkv<<<gq, 256, 0, stream>>>(Qc, Kc, Vc, Wqc, Wkc, Wvc, qh, kh, vT);

    // fused scores + softmax + PV: 4096 one-wave blocks, whole grid resident
    dim3 ga(S_LEN / 16, 1, NB * NH);
    attn_fused<<<ga, 64, 0, stream>>>(qh, kh, vT, prev, scores, attn, ctx);

    // output projection (256 blocks)
    dim3 gp(DM / 128, BS / 128, 1);
    gemm_out<<<gp, 256, 0, stream>>>(ctx, Woc, out);
}

// Round 12
// 631.410 us; speedup vs baseline: 1.1481x; 1.1481x over previous
//
#include <hip/hip_runtime.h>

#define S_LEN 2048
#define NH 16
#define DH 64
#define DM 1024
#define NB 2
#define BS 4096  // NB*S_LEN

typedef __attribute__((ext_vector_type(4))) float f32x4;
typedef __attribute__((ext_vector_type(8))) short bfrag;  // 8 bf16 in 4 VGPRs

__device__ __forceinline__ unsigned short f2bf(float f) {
    unsigned u = __builtin_bit_cast(unsigned, f);
    u += 0x7FFFu + ((u >> 16) & 1u);
    return (unsigned short)(u >> 16);
}

// async global->LDS, 16B per lane; LDS dest must be wave-uniform base (+lane*16 implicit)
__device__ __forceinline__ void gld16(const unsigned short* g, unsigned short* l) {
    __builtin_amdgcn_global_load_lds((const __attribute__((address_space(1))) void*)g,
                                     (__attribute__((address_space(3))) void*)l, 16, 0, 0);
}

// in-wave LDS ordering: DS ops are in-order per wave; drain lgkm then pin order
__device__ __forceinline__ void lds_fence() {
    asm volatile("s_waitcnt lgkmcnt(0)" ::: "memory");
    __builtin_amdgcn_sched_barrier(0);
}

// ---------------- all 7 fp32 -> bf16 casts in one kernel ----------------
__global__ __launch_bounds__(256) void cast_all(const float* __restrict__ Q,
                                                const float* __restrict__ K,
                                                const float* __restrict__ V,
                                                const float* __restrict__ Wq,
                                                const float* __restrict__ Wk,
                                                const float* __restrict__ Wv,
                                                const float* __restrict__ Wo,
                                                unsigned short* __restrict__ Qc,
                                                unsigned short* __restrict__ Kc,
                                                unsigned short* __restrict__ Vc,
                                                unsigned short* __restrict__ Wqc,
                                                unsigned short* __restrict__ Wkc,
                                                unsigned short* __restrict__ Wvc,
                                                unsigned short* __restrict__ Woc) {
    int i = blockIdx.x * 256 + threadIdx.x;  // over 4,194,304 float4 chunks
    const float* src;
    unsigned short* dst;
    int off;
    if (i < 3145728) {                       // Q/K/V: 3 x 2^20 chunks
        int w = i >> 20;
        off = i & 1048575;
        src = (w == 0) ? Q : (w == 1) ? K : V;
        dst = (w == 0) ? Qc : (w == 1) ? Kc : Vc;
    } else {                                 // weights: 4 x 2^18 chunks
        int j = i - 3145728;
        int w = j >> 18;
        off = j & 262143;
        src = (w == 0) ? Wq : (w == 1) ? Wk : (w == 2) ? Wv : Wo;
        dst = (w == 0) ? Wqc : (w == 1) ? Wkc : (w == 2) ? Wvc : Woc;
    }
    float4 v = reinterpret_cast<const float4*>(src)[off];
    ushort4 o;
    o.x = f2bf(v.x); o.y = f2bf(v.y); o.z = f2bf(v.z); o.w = f2bf(v.w);
    reinterpret_cast<ushort4*>(dst)[off] = o;
}

// ================= combined QKV projection (m97 structure) =================
__global__ __launch_bounds__(256) void gemm_qkv(const unsigned short* __restrict__ Qc,
                                                const unsigned short* __restrict__ Kc,
                                                const unsigned short* __restrict__ Vc,
                                                const unsigned short* __restrict__ Wqc,
                                                const unsigned short* __restrict__ Wkc,
                                                const unsigned short* __restrict__ Wvc,
                                                unsigned short* __restrict__ qh,
                                                unsigned short* __restrict__ kh,
                                                unsigned short* __restrict__ vT) {
    const int z = blockIdx.z;
    const unsigned short* A = (z == 0) ? Qc : (z == 1) ? Kc : Vc;
    const unsigned short* B = (z == 0) ? Wqc : (z == 1) ? Wkc : Wvc;
    const int tid = threadIdx.x, lane = tid & 63;
    const int l15 = lane & 15, lhi = lane >> 4;
    const int w = tid >> 6, wr = w >> 1, wc = w & 1;
    const int m0 = blockIdx.y * 128, n0 = blockIdx.x * 128;
    const int K = DM;
    const int lr8 = lane >> 3;             // row-in-8-row-group
    const int csw = (lane & 7) ^ lr8;      // swizzled 16B-chunk index (8 chunks/row)

    __shared__ unsigned short sA[128 * 64];
    __shared__ unsigned short sB[128 * 64];

    f32x4 acc[4][4];
#pragma unroll
    for (int i = 0; i < 4; ++i)
#pragma unroll
        for (int j = 0; j < 4; ++j) acc[i][j] = (f32x4){0.f, 0.f, 0.f, 0.f};

    for (int t = 0; t < 16; ++t) {
        const int k0 = t * 64;
#pragma unroll
        for (int i = 0; i < 4; ++i) {
            int g = w * 4 + i;
            int row = g * 8 + lr8;
            gld16(A + (size_t)(m0 + row) * K + k0 + csw * 8, sA + g * 512);
            gld16(B + (size_t)(n0 + row) * K + k0 + csw * 8, sB + g * 512);
        }
        __syncthreads();
#pragma unroll
        for (int kk = 0; kk < 2; ++kk) {
            bfrag a[4], b[4];
#pragma unroll
            for (int f = 0; f < 4; ++f) {
                int ra = wr * 64 + f * 16 + l15;
                a[f] = *reinterpret_cast<const bfrag*>(
                    sA + ra * 64 + (((kk * 4 + lhi) ^ (ra & 7)) << 3));
                int rb = wc * 64 + f * 16 + l15;
                b[f] = *reinterpret_cast<const bfrag*>(
                    sB + rb * 64 + (((kk * 4 + lhi) ^ (rb & 7)) << 3));
            }
#pragma unroll
            for (int fm = 0; fm < 4; ++fm)
#pragma unroll
                for (int fn = 0; fn < 4; ++fn)
                    acc[fm][fn] =
                        __builtin_amdgcn_mfma_f32_16x16x32_bf16(a[fm], b[fn], acc[fm][fn], 0, 0, 0);
        }
        __syncthreads();
    }

    if (z == 2) {
#pragma unroll
        for (int fm = 0; fm < 4; ++fm)
#pragma unroll
            for (int fn = 0; fn < 4; ++fn) {
                int sbase = m0 + wr * 64 + fm * 16 + (lhi << 2);
                int gcol = n0 + wc * 64 + fn * 16 + l15;
                int b = sbase >> 11, s = sbase & 2047, h = gcol >> 6, d = gcol & 63;
                ushort4 o;
                o.x = f2bf(acc[fm][fn][0]); o.y = f2bf(acc[fm][fn][1]);
                o.z = f2bf(acc[fm][fn][2]); o.w = f2bf(acc[fm][fn][3]);
                *reinterpret_cast<ushort4*>(vT + ((size_t)(b * NH + h) * DH + d) * S_LEN + s) = o;
            }
    } else {
        unsigned short* Out = (z == 0) ? qh : kh;
#pragma unroll
        for (int fm = 0; fm < 4; ++fm)
#pragma unroll
            for (int fn = 0; fn < 4; ++fn)
#pragma unroll
                for (int r = 0; r < 4; ++r) {
                    int grow = m0 + wr * 64 + fm * 16 + (lhi << 2) + r;
                    int gcol = n0 + wc * 64 + fn * 16 + l15;
                    int b = grow >> 11, s = grow & 2047, h = gcol >> 6, d = gcol & 63;
                    Out[((size_t)(b * NH + h) * S_LEN + s) * DH + d] = f2bf(acc[fm][fn][r]);
                }
    }
}

// ================= output projection =================
__global__ __launch_bounds__(256) void gemm_out(const unsigned short* __restrict__ A,
                                                const unsigned short* __restrict__ B,
                                                float* __restrict__ Out) {
    const int tid = threadIdx.x, lane = tid & 63;
    const int l15 = lane & 15, lhi = lane >> 4;
    const int w = tid >> 6, wr = w >> 1, wc = w & 1;
    const int m0 = blockIdx.y * 128, n0 = blockIdx.x * 128;
    const int K = DM, N = DM;
    const int lr8 = lane >> 3;
    const int csw = (lane & 7) ^ lr8;

    __shared__ unsigned short sA[128 * 64];
    __shared__ unsigned short sB[128 * 64];

    f32x4 acc[4][4];
#pragma unroll
    for (int i = 0; i < 4; ++i)
#pragma unroll
        for (int j = 0; j < 4; ++j) acc[i][j] = (f32x4){0.f, 0.f, 0.f, 0.f};

    for (int t = 0; t < 16; ++t) {
        const int k0 = t * 64;
#pragma unroll
        for (int i = 0; i < 4; ++i) {
            int g = w * 4 + i;
            int row = g * 8 + lr8;
            gld16(A + (size_t)(m0 + row) * K + k0 + csw * 8, sA + g * 512);
            gld16(B + (size_t)(n0 + row) * K + k0 + csw * 8, sB + g * 512);
        }
        __syncthreads();
#pragma unroll
        for (int kk = 0; kk < 2; ++kk) {
            bfrag a[4], b[4];
#pragma unroll
            for (int f = 0; f < 4; ++f) {
                int ra = wr * 64 + f * 16 + l15;
                a[f] = *reinterpret_cast<const bfrag*>(
                    sA + ra * 64 + (((kk * 4 + lhi) ^ (ra & 7)) << 3));
                int rb = wc * 64 + f * 16 + l15;
                b[f] = *reinterpret_cast<const bfrag*>(
                    sB + rb * 64 + (((kk * 4 + lhi) ^ (rb & 7)) << 3));
            }
#pragma unroll
            for (int fm = 0; fm < 4; ++fm)
#pragma unroll
                for (int fn = 0; fn < 4; ++fn)
                    acc[fm][fn] =
                        __builtin_amdgcn_mfma_f32_16x16x32_bf16(a[fm], b[fn], acc[fm][fn], 0, 0, 0);
        }
        __syncthreads();
    }

#pragma unroll
    for (int fm = 0; fm < 4; ++fm)
#pragma unroll
        for (int fn = 0; fn < 4; ++fn)
#pragma unroll
            for (int r = 0; r < 4; ++r) {
                int grow = m0 + wr * 64 + fm * 16 + (lhi << 2) + r;
                int gcol = n0 + wc * 64 + fn * 16 + l15;
                Out[(size_t)grow * N + gcol] = acc[fm][fn][r];
            }
}

// ================= fused scores + softmax + PV: 1-wave blocks + COALESCED I/O =====
// All HBM streams (prev, scores, attn) go through an in-wave 4KB LDS transpose so
// each global instruction covers 4 rows x 256B contiguous segments (was 16x16-64B).
// Coalesced mapping: chunk i: row = i*4 + (lane>>4), col = (lane&15)*4.
// MFMA layout (swapped operands): lane owns q-row (lane&15), cols f*16+(lane>>4)*4.
// DS ops are in-order within a wave -> lgkmcnt-only fences, zero barriers.
__global__ __launch_bounds__(64, 3) void attn_fused(const unsigned short* __restrict__ qh,
                                                    const unsigned short* __restrict__ kh,
                                                    const unsigned short* __restrict__ vT,
                                                    const float* __restrict__ prev,
                                                    float* __restrict__ scores,
                                                    float* __restrict__ attn,
                                                    unsigned short* __restrict__ ctx) {
    const int z = blockIdx.z;         // b*NH + h
    const int m0 = blockIdx.x * 16;   // Q strip base (16 rows per 1-wave block)
    const int lane = threadIdx.x & 63;
    const int l15 = lane & 15, lhi = lane >> 4;
    const int crow = lane >> 4;       // row-in-4 for coalesced chunks
    const int ccol = (lane & 15) * 4; // col base for coalesced chunks

    __shared__ float sT[16 * 64];     // 4KB transpose buffer (bf16-aliased in phase 2)
    unsigned short* sB = reinterpret_cast<unsigned short*>(sT);

    const unsigned short* Qz = qh + (size_t)z * S_LEN * DH;
    const unsigned short* Kz = kh + (size_t)z * S_LEN * DH;
    const unsigned short* Vz = vT + (size_t)z * DH * S_LEN;
    const size_t zbase = (size_t)z * S_LEN * S_LEN;
    const float scale = 0.125f;  // 1/sqrt(64)

    // coalesced row offsets (shared by prev/scores/attn: same geometry)
    size_t ro[4];
#pragma unroll
    for (int i = 0; i < 4; ++i)
        ro[i] = zbase + (size_t)(m0 + i * 4 + crow) * S_LEN + ccol;

    // Q fragments: loaded once (MFMA layout)
    bfrag qf[2];
#pragma unroll
    for (int kk = 0; kk < 2; ++kk)
        qf[kk] = *reinterpret_cast<const bfrag*>(Qz + (size_t)(m0 + l15) * DH + kk * 32 +
                                                 lhi * 8);

    float m_r[4], l_r[4];
#pragma unroll
    for (int i = 0; i < 4; ++i) { m_r[i] = -1e30f; l_r[i] = 0.f; }

    // prologue: K tile 0 (scattered, L2) + prev tile 0 (coalesced, NT)
    bfrag kf[2][4];
#pragma unroll
    for (int kk = 0; kk < 2; ++kk)
#pragma unroll
        for (int f = 0; f < 4; ++f)
            kf[kk][f] = *reinterpret_cast<const bfrag*>(
                Kz + (size_t)(f * 16 + l15) * DH + kk * 32 + lhi * 8);
    f32x4 pv4[4];
#pragma unroll
    for (int i = 0; i < 4; ++i)
        pv4[i] = __builtin_nontemporal_load(reinterpret_cast<const f32x4*>(prev + ro[i]));

    // ---------- phase 1: 32 x 64-col tiles ----------
    for (int kt = 0; kt < 32; ++kt) {
        const int n0 = kt * 64;

        f32x4 acc[4];
#pragma unroll
        for (int f = 0; f < 4; ++f) acc[f] = (f32x4){0.f, 0.f, 0.f, 0.f};
#pragma unroll
        for (int kk = 0; kk < 2; ++kk)
#pragma unroll
            for (int f = 0; f < 4; ++f)
                acc[f] = __builtin_amdgcn_mfma_f32_16x16x32_bf16(kf[kk][f], qf[kk], acc[f], 0, 0, 0);

        // reload kf for kt+1 (covered by transpose+softmax chain below)
        if (kt < 31) {
            const int n1 = n0 + 64;
#pragma unroll
            for (int kk = 0; kk < 2; ++kk)
#pragma unroll
                for (int f = 0; f < 4; ++f)
                    kf[kk][f] = *reinterpret_cast<const bfrag*>(
                        Kz + (size_t)(n1 + f * 16 + l15) * DH + kk * 32 + lhi * 8);
        }

        // transpose: MFMA layout -> LDS (16B chunks, XOR-swizzled)
#pragma unroll
        for (int f = 0; f < 4; ++f)
            *reinterpret_cast<f32x4*>(sT + l15 * 64 + (((f * 4 + lhi) ^ (l15 & 7)) * 4)) = acc[f];
        lds_fence();
        // read back coalesced: chunk i: row i*4+crow, 16B chunk index l15
        f32x4 sc[4];
#pragma unroll
        for (int i = 0; i < 4; ++i) {
            int r = i * 4 + crow;
            sc[i] = *reinterpret_cast<const f32x4*>(sT + r * 64 + ((l15 ^ (r & 7)) * 4));
        }

        // s = acc*scale + prev (coalesced); refill prev(kt+1); store scores (256B segs)
#pragma unroll
        for (int i = 0; i < 4; ++i)
#pragma unroll
            for (int r = 0; r < 4; ++r) sc[i][r] = sc[i][r] * scale + pv4[i][r];
        if (kt < 31) {
            const int n1 = n0 + 64;
#pragma unroll
            for (int i = 0; i < 4; ++i)
                pv4[i] = __builtin_nontemporal_load(
                    reinterpret_cast<const f32x4*>(prev + ro[i] + n1));
        }
#pragma unroll
        for (int i = 0; i < 4; ++i)
            *reinterpret_cast<f32x4*>(scores + ro[i] + n0) = sc[i];

        // online softmax per chunk-row (row's 64 cols live in the 16 l15-lanes)
#pragma unroll
        for (int i = 0; i < 4; ++i) {
            float pm = fmaxf(fmaxf(sc[i][0], sc[i][1]), fmaxf(sc[i][2], sc[i][3]));
            pm = fmaxf(pm, __shfl_xor(pm, 1));
            pm = fmaxf(pm, __shfl_xor(pm, 2));
            pm = fmaxf(pm, __shfl_xor(pm, 4));
            pm = fmaxf(pm, __shfl_xor(pm, 8));
            float mnew = fmaxf(m_r[i], pm);
            float ps = __expf(sc[i][0] - mnew) + __expf(sc[i][1] - mnew) +
                       __expf(sc[i][2] - mnew) + __expf(sc[i][3] - mnew);
            ps += __shfl_xor(ps, 1);
            ps += __shfl_xor(ps, 2);
            ps += __shfl_xor(ps, 4);
            ps += __shfl_xor(ps, 8);
            l_r[i] = l_r[i] * __expf(m_r[i] - mnew) + ps;
            m_r[i] = mnew;
        }
    }

    float inv_l[4];
#pragma unroll
    for (int i = 0; i < 4; ++i) inv_l[i] = 1.0f / l_r[i];

    // ---------- phase 2: reverse order (hottest scores first) ----------
    f32x4 acco[4];
#pragma unroll
    for (int f = 0; f < 4; ++f) acco[f] = (f32x4){0.f, 0.f, 0.f, 0.f};

    // prologue: V tile 31 (scattered, L2) + scores tile 31 (coalesced)
    bfrag vf[2][4];
#pragma unroll
    for (int kk = 0; kk < 2; ++kk)
#pragma unroll
        for (int f = 0; f < 4; ++f)
            vf[kk][f] = *reinterpret_cast<const bfrag*>(
                Vz + (size_t)(f * 16 + l15) * S_LEN + 31 * 64 + kk * 32 + lhi * 8);
    f32x4 sv[4];
#pragma unroll
    for (int i = 0; i < 4; ++i)
        sv[i] = *reinterpret_cast<const f32x4*>(scores + ro[i] + 31 * 64);

    for (int kt = 31; kt >= 0; --kt) {
        const int n0 = kt * 64;
        // p = exp(s-m)/l (coalesced); NT-store attn (256B segs); pack bf16 -> LDS
#pragma unroll
        for (int i = 0; i < 4; ++i) {
            int r = i * 4 + crow;
            f32x4 p4;
#pragma unroll
            for (int rr = 0; rr < 4; ++rr) p4[rr] = __expf(sv[i][rr] - m_r[i]) * inv_l[i];
            __builtin_nontemporal_store(p4, reinterpret_cast<f32x4*>(attn + ro[i] + n0));
            ushort4 pb;
            pb.x = f2bf(p4[0]); pb.y = f2bf(p4[1]); pb.z = f2bf(p4[2]); pb.w = f2bf(p4[3]);
            // bf16 tile [16][64]: 8B chunk index l15, XOR-swizzled
            *reinterpret_cast<ushort4*>(sB + r * 64 + ((l15 ^ (r & 7)) * 4)) = pb;
        }
        lds_fence();
        // read pf in MFMA layout: row l15, cols kk*32+lhi*8 (two swizzled 8B chunks)
        bfrag pf[2];
#pragma unroll
        for (int kk = 0; kk < 2; ++kk) {
            int c0 = kk * 8 + lhi * 2;
            ushort4 lo = *reinterpret_cast<const ushort4*>(sB + l15 * 64 + ((c0 ^ (l15 & 7)) * 4));
            ushort4 hi =
                *reinterpret_cast<const ushort4*>(sB + l15 * 64 + (((c0 + 1) ^ (l15 & 7)) * 4));
            pf[kk][0] = (short)lo.x; pf[kk][1] = (short)lo.y;
            pf[kk][2] = (short)lo.z; pf[kk][3] = (short)lo.w;
            pf[kk][4] = (short)hi.x; pf[kk][5] = (short)hi.y;
            pf[kk][6] = (short)hi.z; pf[kk][7] = (short)hi.w;
        }
        // prefetch next scores tile (coalesced)
        if (kt > 0) {
            const int n1 = n0 - 64;
#pragma unroll
            for (int i = 0; i < 4; ++i)
                sv[i] = *reinterpret_cast<const f32x4*>(scores + ro[i] + n1);
        }
        // O^T += V^T @ P^T
#pragma unroll
        for (int kk = 0; kk < 2; ++kk)
#pragma unroll
            for (int f = 0; f < 4; ++f)
                acco[f] = __builtin_amdgcn_mfma_f32_16x16x32_bf16(vf[kk][f], pf[kk], acco[f], 0, 0, 0);
        // reload vf for kt-1 (covered by next tile's exp/pack chain)
        if (kt > 0) {
            const int n1 = n0 - 64;
#pragma unroll
            for (int kk = 0; kk < 2; ++kk)
#pragma unroll
                for (int f = 0; f < 4; ++f)
                    vf[kk][f] = *reinterpret_cast<const bfrag*>(
                        Vz + (size_t)(f * 16 + l15) * S_LEN + n1 + kk * 32 + lhi * 8);
        }
    }

    // write ctx (b, s, h*DH + d) bf16; lane owns q-row l15, d = f*16 + lhi*4 + r
    const int b = z >> 4, h = z & 15;
    const int s = m0 + l15;
#pragma unroll
    for (int f = 0; f < 4; ++f) {
        int d0 = f * 16 + lhi * 4;
        ushort4 o;
        o.x = f2bf(acco[f][0]); o.y = f2bf(acco[f][1]);
        o.z = f2bf(acco[f][2]); o.w = f2bf(acco[f][3]);
        *reinterpret_cast<ushort4*>(ctx + ((size_t)(b * S_LEN + s)) * DM + h * DH + d0) = o;
    }
}

extern "C" void kernel_launch(void* const* d_in, const int* in_sizes, int n_in, void* d_out,
                              int out_size, void* d_ws, size_t ws_size, hipStream_t stream) {
    const float* Q = (const float*)d_in[0];
    const float* K = (const float*)d_in[1];
    const float* V = (const float*)d_in[2];
    const float* prev = (const float*)d_in[3];
    const float* Wq = (const float*)d_in[4];
    const float* Wk = (const float*)d_in[5];
    const float* Wv = (const float*)d_in[6];
    const float* Wo = (const float*)d_in[7];

    float* out = (float*)d_out;
    float* attn = out + (size_t)BS * DM;
    float* scores = attn + (size_t)NB * NH * S_LEN * S_LEN;

    unsigned short* ws = (unsigned short*)d_ws;
    unsigned short* Qc = ws;
    unsigned short* Kc = Qc + (size_t)BS * DM;
    unsigned short* Vc = Kc + (size_t)BS * DM;
    unsigned short* Wqc = Vc + (size_t)BS * DM;
    unsigned short* Wkc = Wqc + (size_t)DM * DM;
    unsigned short* Wvc = Wkc + (size_t)DM * DM;
    unsigned short* Woc = Wvc + (size_t)DM * DM;
    unsigned short* qh = Woc + (size_t)DM * DM;    // (b,h,s,d) bf16
    unsigned short* kh = qh + (size_t)BS * DM;     // (b,h,s,d) bf16
    unsigned short* vT = kh + (size_t)BS * DM;     // (b,h,d,s) bf16
    unsigned short* ctx = vT + (size_t)BS * DM;    // (b,s,h*d) bf16

    // all casts in one launch
    cast_all<<<16384, 256, 0, stream>>>(Q, K, V, Wq, Wk, Wv, Wo,
                                        Qc, Kc, Vc, Wqc, Wkc, Wvc, Woc);

    // combined QKV projections (768 blocks)
    dim3 gq(DM / 128, BS / 128, 3);
    gemm_qkv<<<gq, 256, 0, stream>>>(Qc, Kc, Vc, Wqc, Wkc, Wvc, qh, kh, vT);

    // fused scores + softmax + PV: 4096 one-wave blocks, coalesced HBM streams
    dim3 ga(S_LEN / 16, 1, NB * NH);
    attn_fused<<<ga, 64, 0, stream>>>(qh, kh, vT, prev, scores, attn, ctx);

    // output projection (256 blocks)
    dim3 gp(DM / 128, BS / 128, 1);
    gemm_out<<<gp, 256, 0, stream>>>(ctx, Woc, out);
}